// Round 7
// baseline (184.768 us; speedup 1.0000x reference)
//
#include <hip/hip_runtime.h>
#include <hip/hip_bf16.h>
#include <stdint.h>

// Problem constants
#define B_  2
#define S_  2048
#define D_  1024
#define H_  16
#define DQ_ 64
#define QT_ (S_/64)   // 32 k-tiles (64 keys) per (b,h)
// exp(x*0.125 - 16) = exp2(x*0.18033688 - 23.083121)
#define EXPC1_ 0.18033688f
#define EXPC2_ (-23.083121f)

typedef float f32x4 __attribute__((ext_vector_type(4)));
typedef short bf16x8 __attribute__((ext_vector_type(8)));

__device__ __forceinline__ unsigned short f2bf(float f) {
    uint32_t u = __float_as_uint(f);
    u += 0x7fffu + ((u >> 16) & 1u);   // round-to-nearest-even
    return (unsigned short)(u >> 16);
}
__device__ __forceinline__ float bf2f(unsigned short u) {
    return __uint_as_float(((uint32_t)u) << 16);
}
__device__ __forceinline__ bf16x8 packbf8(float4 a, float4 b) {
    bf16x8 r;
    r[0]=(short)f2bf(a.x); r[1]=(short)f2bf(a.y);
    r[2]=(short)f2bf(a.z); r[3]=(short)f2bf(a.w);
    r[4]=(short)f2bf(b.x); r[5]=(short)f2bf(b.y);
    r[6]=(short)f2bf(b.z); r[7]=(short)f2bf(b.w);
    return r;
}
// pack two fp32 -> two bf16 (truncation) in ONE v_perm_b32
__device__ __forceinline__ uint32_t packtrunc(float hi, float lo) {
    return __builtin_amdgcn_perm(__float_as_uint(hi), __float_as_uint(lo),
                                 0x07060302u);
}

// ---------------------------------------------------------------------------
// Kernel 1: prep — K fp32->bf16, Wo fp32->bf16, V transpose->bf16 (+Pv
// column partials for the row-0 mean(V) path). 6144 blocks:
//   [0,1024): V transpose   [1024,5120): K convert   [5120,6144): Wo convert
// ---------------------------------------------------------------------------
__global__ __launch_bounds__(256) void prep_kernel(
    const float* __restrict__ K, const float* __restrict__ V,
    const float* __restrict__ W,
    unsigned short* __restrict__ Kb, unsigned short* __restrict__ Vt,
    unsigned short* __restrict__ Wb, float* __restrict__ Pv)
{
    __shared__ unsigned short Ls[64][72];
    const int blk = blockIdx.x, tid = threadIdx.x;

    if (blk < 1024) {
        const int st = blk & 31, h = (blk >> 5) & 15, b = blk >> 9;
        {
            int row = tid >> 2, col0 = (tid & 3) * 16;   // row=s-in-tile, col=dq
            const float* src = V + (((size_t)b*S_ + (size_t)st*64 + row)*D_ + h*64 + col0);
            float4 f0 = ((const float4*)src)[0];
            float4 f1 = ((const float4*)src)[1];
            float4 f2 = ((const float4*)src)[2];
            float4 f3 = ((const float4*)src)[3];
            unsigned short* d = &Ls[row][col0];
            d[0]=f2bf(f0.x); d[1]=f2bf(f0.y); d[2]=f2bf(f0.z); d[3]=f2bf(f0.w);
            d[4]=f2bf(f1.x); d[5]=f2bf(f1.y); d[6]=f2bf(f1.z); d[7]=f2bf(f1.w);
            d[8]=f2bf(f2.x); d[9]=f2bf(f2.y); d[10]=f2bf(f2.z); d[11]=f2bf(f2.w);
            d[12]=f2bf(f3.x); d[13]=f2bf(f3.y); d[14]=f2bf(f3.z); d[15]=f2bf(f3.w);
        }
        __syncthreads();
        {
            int d = tid >> 2, scol = (tid & 3) * 16;     // d = dq row of Vt
            unsigned short tmp[16];
            float psum = 0.f;
            #pragma unroll
            for (int i = 0; i < 16; ++i) {
                unsigned short u = Ls[scol + i][d];
                tmp[i] = u;
                psum += bf2f(u);
            }
            unsigned short* dst = Vt + ((size_t)((b*H_ + h)*64 + d)*S_ + st*64 + scol);
            ((uint4*)dst)[0] = *((uint4*)tmp);
            ((uint4*)dst)[1] = *((uint4*)(tmp + 8));
            psum += __shfl_xor(psum, 1);
            psum += __shfl_xor(psum, 2);
            if ((tid & 3) == 0)
                Pv[((size_t)(b*H_ + h)*64 + d)*32 + st] = psum;
        }
    } else if (blk < 5120) {
        int i = (blk - 1024)*256 + tid;     // < B*S*D/4
        float4 f = ((const float4*)K)[i];
        ushort4 o;
        o.x = f2bf(f.x); o.y = f2bf(f.y); o.z = f2bf(f.z); o.w = f2bf(f.w);
        ((ushort4*)Kb)[i] = o;
    } else {
        int i = (blk - 5120)*256 + tid;     // < D*D/4
        float4 f = ((const float4*)W)[i];
        ushort4 o;
        o.x = f2bf(f.x); o.y = f2bf(f.y); o.z = f2bf(f.z); o.w = f2bf(f.w);
        ((ushort4*)Wb)[i] = o;
    }
}

// ---------------------------------------------------------------------------
// Kernel 2: split-K flash attention. 256-thr blocks = 4 waves x 32 q-rows =
// 128-row q-group. Fixed-max softmax -> partials (O, l) over disjoint key
// chunks combine by pure addition. Block (bh, pp, c): chunk c (of 2) of the
// key range for group pp at t=0 and group 15-pp at t=1; chunk sizes
// (pp+1) + (16-pp) = 17 iters for EVERY block. Grid 512 = 2 blocks/CU,
// 8 waves/CU; bid = bh + 32*(2*pp+c) keeps each bh on one XCD.
// S computed transposed (S^T = K Q^T): P written to LDS as b64, read b128.
// bf16 pack via v_perm (trunc). Partials: Opart bf16 [bh][g*2+c][128][64],
// lpart fp32 [bh][g*2+c][128].
// ---------------------------------------------------------------------------
__global__ __launch_bounds__(256, 2) void attn_kernel(
    const float* __restrict__ Q,
    const unsigned short* __restrict__ Kb,
    const unsigned short* __restrict__ Vtb,
    unsigned short* __restrict__ Opart,
    float* __restrict__ lpart,
    const int* __restrict__ maskp)
{
    __shared__ unsigned short Ks [2][64][72];   // [buf][key][dq]
    __shared__ unsigned short Vts[2][64][72];   // [buf][dq][key]
    __shared__ unsigned short Ps [4][32][72];   // per-wave P: [q][key]

    const int bid = blockIdx.x;
    const int bh = bid & 31, sc = bid >> 5;     // sc = 2*pp + c
    const int pp = sc >> 1, c = sc & 1;
    const int h = bh & 15, b = bh >> 4;
    const int tid  = threadIdx.x;
    const int wave = tid >> 6, lane = tid & 63;
    const int quad = lane >> 4, ln = lane & 15;
    const int maskv = maskp[0];

    // staging: 256 threads cover 64 rows x 64 cols (32B per tensor each)
    const int srow = tid >> 2, scol = (tid & 3)*16;
    const unsigned short* kbase =
        Kb + (((size_t)b*S_ + srow)*D_ + h*64 + scol);          // + j*64*D_
    const unsigned short* vbase =
        Vtb + ((size_t)((b*H_ + h)*64 + srow)*S_ + scol);       // + j*64

    for (int t = 0; t < 2; ++t) {
        const int g = t ? (15 - pp) : pp;            // 128-row q-group
        const int n = maskv ? (2*g + 2) : QT_;       // tiles in key range
        const int j0 = (c*n) >> 1, j1 = ((c+1)*n) >> 1;
        const int qw0 = g*128 + wave*32;             // wave's first q-row

        // Q B-fragments: fp32 global -> bf16 regs.
        bf16x8 bq[2][2];
        #pragma unroll
        for (int qt2 = 0; qt2 < 2; ++qt2) {
            const float* qr = Q + (((size_t)b*S_ + qw0 + qt2*16 + ln)*D_
                                   + h*64 + quad*8);
            #pragma unroll
            for (int dqs = 0; dqs < 2; ++dqs) {
                float4 f0 = ((const float4*)(qr + dqs*32))[0];
                float4 f1 = ((const float4*)(qr + dqs*32))[1];
                bq[qt2][dqs] = packbf8(f0, f1);
            }
        }

        // prefetch first tile of chunk
        uint4 k0 = ((const uint4*)(kbase + (size_t)j0*64*D_))[0];
        uint4 k1 = ((const uint4*)(kbase + (size_t)j0*64*D_))[1];
        uint4 v0 = ((const uint4*)(vbase + j0*64))[0];
        uint4 v1 = ((const uint4*)(vbase + j0*64))[1];

        f32x4 o[2][4] = {};               // [qt2][dd] PV accum (C-layout)
        float l4[2] = {0.f, 0.f};         // per-lane l partial (q = ln)

        if (t) __syncthreads();           // protect LDS from previous pass

        for (int j = j0; j < j1; ++j) {
            const int cur = j & 1;
            *((uint4*)&Ks [cur][srow][scol])   = k0;
            *((uint4*)&Ks [cur][srow][scol+8]) = k1;
            *((uint4*)&Vts[cur][srow][scol])   = v0;
            *((uint4*)&Vts[cur][srow][scol+8]) = v1;
            if (j + 1 < j1) {
                const unsigned short* kp = kbase + (size_t)(j+1)*64*D_;
                const unsigned short* vp = vbase + (j+1)*64;
                k0 = ((const uint4*)kp)[0]; k1 = ((const uint4*)kp)[1];
                v0 = ((const uint4*)vp)[0]; v1 = ((const uint4*)vp)[1];
            }
            __syncthreads();

            // fully-masked tile for this wave's 32 rows? contribute nothing.
            if (maskv && j*64 >= qw0 + 32) continue;

            // ---- S^T = K Q^T : s[kt][qt2], D[m=key][n=q] ----
            f32x4 s[4][2] = {};
            #pragma unroll
            for (int dqs = 0; dqs < 2; ++dqs)
                #pragma unroll
                for (int kt = 0; kt < 4; ++kt) {
                    bf16x8 aK = *(const bf16x8*)&Ks[cur][kt*16 + ln][dqs*32 + quad*8];
                    #pragma unroll
                    for (int qt2 = 0; qt2 < 2; ++qt2)
                        s[kt][qt2] = __builtin_amdgcn_mfma_f32_16x16x32_bf16(
                            aK, bq[qt2][dqs], s[kt][qt2], 0,0,0);
                }

            // ---- P = exp2(S*c1 + c2); l partial; Ps b64 writes (perm) ----
            const int needmask = maskv && (j*64 + 63 >= qw0);
            #pragma unroll
            for (int qt2 = 0; qt2 < 2; ++qt2) {
                const int qgl = qw0 + qt2*16 + ln;     // global q row
                #pragma unroll
                for (int kt = 0; kt < 4; ++kt) {
                    const int kg = j*64 + kt*16 + quad*4;
                    float e[4];
                    #pragma unroll
                    for (int r = 0; r < 4; ++r) {
                        float v = exp2f(fmaf(s[kt][qt2][r], EXPC1_, EXPC2_));
                        if (needmask && (kg + r) >= qgl) v = 0.f;
                        e[r] = v;
                    }
                    l4[qt2] += (e[0] + e[1]) + (e[2] + e[3]);
                    uint2 w;
                    w.x = packtrunc(e[1], e[0]);
                    w.y = packtrunc(e[3], e[2]);
                    *((uint2*)&Ps[wave][qt2*16 + ln][kt*16 + quad*4]) = w;
                }
            }
            // no barrier: Ps is per-wave; DS pipe in-order per wave

            // ---- O += P V : A = Ps (m=q, k=key), B = Vts (n=dq, k=key) ----
            bf16x8 ap[2][2];
            #pragma unroll
            for (int qt2 = 0; qt2 < 2; ++qt2)
                #pragma unroll
                for (int ks2 = 0; ks2 < 2; ++ks2)
                    ap[qt2][ks2] = *(const bf16x8*)&Ps[wave][qt2*16 + ln][ks2*32 + quad*8];
            #pragma unroll
            for (int ks2 = 0; ks2 < 2; ++ks2)
                #pragma unroll
                for (int dd = 0; dd < 4; ++dd) {
                    bf16x8 bv = *(const bf16x8*)&Vts[cur][dd*16 + ln][ks2*32 + quad*8];
                    #pragma unroll
                    for (int qt2 = 0; qt2 < 2; ++qt2)
                        o[qt2][dd] = __builtin_amdgcn_mfma_f32_16x16x32_bf16(
                            ap[qt2][ks2], bv, o[qt2][dd], 0,0,0);
                }
        }

        // ---- epilogue: store partials (NO normalization) ----
        // l total per q: lanes sharing q=ln are {ln, ln^16, ln^32, ln^48}
        #pragma unroll
        for (int qt2 = 0; qt2 < 2; ++qt2) {
            l4[qt2] += __shfl_xor(l4[qt2], 16);
            l4[qt2] += __shfl_xor(l4[qt2], 32);
        }
        const size_t slot = (size_t)bh*32 + g*2 + c;
        if (quad == 0) {   // lanes 0-15 hold q = ln totals
            #pragma unroll
            for (int qt2 = 0; qt2 < 2; ++qt2)
                lpart[slot*128 + wave*32 + qt2*16 + ln] = l4[qt2];
        }
        unsigned short* ob = Opart + slot*(128*64);
        #pragma unroll
        for (int qt2 = 0; qt2 < 2; ++qt2)
            #pragma unroll
            for (int dd = 0; dd < 4; ++dd)
                #pragma unroll
                for (int r = 0; r < 4; ++r) {
                    int q8 = wave*32 + qt2*16 + quad*4 + r;
                    int dq = dd*16 + ln;
                    ob[q8*64 + dq] = f2bf(o[qt2][dd][r]);
                }
        __syncthreads();   // before next pass re-stages buffers
    }
}

// ---------------------------------------------------------------------------
// Kernel 2b: reduce partials -> ctx bf16.  Grid 512 = (bh, g); 256 thr;
// thread owns (q = tid>>1, dq half = (tid&1)*32): sums 2 chunk partials,
// divides by l, writes ctx. Row q==0 under mask -> mean(V) from Pv.
// ---------------------------------------------------------------------------
__global__ __launch_bounds__(256) void reduce_kernel(
    const unsigned short* __restrict__ Opart,
    const float* __restrict__ lpart,
    const float* __restrict__ Pv,
    unsigned short* __restrict__ ctx,
    const int* __restrict__ maskp)
{
    const int blk = blockIdx.x;          // bh*16 + g
    const int bh = blk >> 4, g = blk & 15;
    const int h = bh & 15, b = bh >> 4;
    const int tid = threadIdx.x;
    const int q = tid >> 1, dq0 = (tid & 1)*32;
    const int gq = g*128 + q;
    const int maskv = maskp[0];

    unsigned short outv[32];
    if (maskv && gq == 0) {
        #pragma unroll 4
        for (int i = 0; i < 32; ++i) {
            const float* p = Pv + ((size_t)bh*64 + dq0 + i)*32;
            float s = 0.f;
            #pragma unroll
            for (int k = 0; k < 32; ++k) s += p[k];
            outv[i] = f2bf(s * (1.0f/S_));
        }
    } else {
        float acc[32];
        #pragma unroll
        for (int i = 0; i < 32; ++i) acc[i] = 0.f;
        float l = 0.f;
        const size_t slot0 = (size_t)bh*32 + g*2;
        #pragma unroll
        for (int c = 0; c < 2; ++c) {
            const unsigned short* op = Opart + (slot0 + c)*(128*64) + q*64 + dq0;
            #pragma unroll
            for (int u = 0; u < 4; ++u) {
                uint4 v = ((const uint4*)op)[u];
                acc[u*8+0] += bf2f((unsigned short)(v.x & 0xffff));
                acc[u*8+1] += bf2f((unsigned short)(v.x >> 16));
                acc[u*8+2] += bf2f((unsigned short)(v.y & 0xffff));
                acc[u*8+3] += bf2f((unsigned short)(v.y >> 16));
                acc[u*8+4] += bf2f((unsigned short)(v.z & 0xffff));
                acc[u*8+5] += bf2f((unsigned short)(v.z >> 16));
                acc[u*8+6] += bf2f((unsigned short)(v.w & 0xffff));
                acc[u*8+7] += bf2f((unsigned short)(v.w >> 16));
            }
            l += lpart[(slot0 + c)*128 + q];
        }
        float inv = 1.0f / l;
        #pragma unroll
        for (int i = 0; i < 32; ++i) outv[i] = f2bf(acc[i]*inv);
    }
    unsigned short* dst = ctx + ((size_t)b*S_ + gq)*D_ + h*64 + dq0;
    #pragma unroll
    for (int u = 0; u < 4; ++u)
        ((uint4*)dst)[u] = ((uint4*)outv)[u];
}

// ---------------------------------------------------------------------------
// Kernel 3: out = ctx @ Wo^T + bias   (M=4096, N=1024, K=1024, bf16 MFMA)
// 64x128 tile, 4 waves (each 64x32), BK=64, double-buffered, 1 barrier/kt.
// Grid (8, 64) = 512 blocks; bid%8 = nt0 -> per-XCD Wo panel locality.
// ---------------------------------------------------------------------------
__global__ __launch_bounds__(256, 2) void proj_kernel(
    const unsigned short* __restrict__ A,    // ctx bf16 [4096][1024]
    const unsigned short* __restrict__ Bw,   // Wo bf16  [1024][1024]
    const float* __restrict__ bias,
    float* __restrict__ out)
{
    __shared__ unsigned short As[2][64][72];
    __shared__ unsigned short Bs[2][128][72];
    const int nt0 = blockIdx.x;   // 0..7   (N panel)
    const int mt0 = blockIdx.y;   // 0..63  (M panel)
    const int tid  = threadIdx.x;
    const int wave = tid >> 6, lane = tid & 63;
    const int quad = lane >> 4, ln = lane & 15;

    const int arow = tid >> 2, acol = (tid & 3)*16;   // A: 64 rows x 64 cols
    const int brow = tid >> 1, bcol = (tid & 1)*32;   // B: 128 rows x 64 cols
    const unsigned short* aptr = A  + ((size_t)(mt0*64  + arow)*1024 + acol);
    const unsigned short* bptr = Bw + ((size_t)(nt0*128 + brow)*1024 + bcol);

    uint4 a0 = ((const uint4*)aptr)[0], a1 = ((const uint4*)aptr)[1];
    uint4 b0 = ((const uint4*)bptr)[0], b1 = ((const uint4*)bptr)[1],
          b2 = ((const uint4*)bptr)[2], b3 = ((const uint4*)bptr)[3];

    f32x4 acc[4][2] = {};

    for (int kt = 0; kt < 16; ++kt) {
        const int cur = kt & 1;
        *((uint4*)&As[cur][arow][acol])    = a0;
        *((uint4*)&As[cur][arow][acol+8])  = a1;
        *((uint4*)&Bs[cur][brow][bcol])    = b0;
        *((uint4*)&Bs[cur][brow][bcol+8])  = b1;
        *((uint4*)&Bs[cur][brow][bcol+16]) = b2;
        *((uint4*)&Bs[cur][brow][bcol+24]) = b3;
        uint4 na0, na1, nb0, nb1, nb2, nb3;
        if (kt < 15) {
            const unsigned short* ap = aptr + (kt+1)*64;
            const unsigned short* bp = bptr + (kt+1)*64;
            na0 = ((const uint4*)ap)[0]; na1 = ((const uint4*)ap)[1];
            nb0 = ((const uint4*)bp)[0]; nb1 = ((const uint4*)bp)[1];
            nb2 = ((const uint4*)bp)[2]; nb3 = ((const uint4*)bp)[3];
        }
        __syncthreads();
        #pragma unroll
        for (int ks = 0; ks < 2; ++ks) {
            bf16x8 am[4], bn[2];
            #pragma unroll
            for (int i = 0; i < 4; ++i)
                am[i] = *(const bf16x8*)&As[cur][i*16 + ln][ks*32 + quad*8];
            #pragma unroll
            for (int i = 0; i < 2; ++i)
                bn[i] = *(const bf16x8*)&Bs[cur][wave*32 + i*16 + ln][ks*32 + quad*8];
            #pragma unroll
            for (int mi = 0; mi < 4; ++mi)
                #pragma unroll
                for (int ni = 0; ni < 2; ++ni)
                    acc[mi][ni] = __builtin_amdgcn_mfma_f32_16x16x32_bf16(
                        am[mi], bn[ni], acc[mi][ni], 0,0,0);
        }
        a0 = na0; a1 = na1;
        b0 = nb0; b1 = nb1; b2 = nb2; b3 = nb3;
    }

    #pragma unroll
    for (int mi = 0; mi < 4; ++mi)
        #pragma unroll
        for (int ni = 0; ni < 2; ++ni) {
            int row = mt0*64 + mi*16 + quad*4;
            int col = nt0*128 + wave*32 + ni*16 + ln;
            float bv = bias[col];
            #pragma unroll
            for (int r = 0; r < 4; ++r)
                out[(size_t)(row + r)*1024 + col] = acc[mi][ni][r] + bv;
        }
}

// ---------------------------------------------------------------------------
extern "C" void kernel_launch(void* const* d_in, const int* in_sizes, int n_in,
                              void* d_out, int out_size, void* d_ws, size_t ws_size,
                              hipStream_t stream)
{
    const float* Q   = (const float*)d_in[0];
    const float* K   = (const float*)d_in[1];
    const float* V   = (const float*)d_in[2];
    const float* Wo  = (const float*)d_in[3];
    const float* Wb  = (const float*)d_in[4];
    const int* maskp = (const int*)d_in[5];
    float* out = (float*)d_out;

    // workspace layout (ushort units unless noted)
    unsigned short* Kb   = (unsigned short*)d_ws;                 // 8.39 MB
    unsigned short* Vtb  = Kb   + (size_t)B_*S_*D_;               // 8.39 MB
    unsigned short* Wob  = Vtb  + (size_t)B_*S_*D_;               // 2.10 MB
    unsigned short* ctxb = Wob  + (size_t)D_*D_;                  // 8.39 MB
    unsigned short* Opart= ctxb + (size_t)B_*S_*D_;               // 16.8 MB
    float* lpart = (float*)(Opart + (size_t)32*32*128*64);        // 0.52 MB
    float* Pv    = lpart + (size_t)32*32*128;                     // 0.26 MB
    // total ~44.9 MB

    prep_kernel<<<6144, 256, 0, stream>>>(K, V, Wo, Kb, Vtb, Wob, Pv);
    attn_kernel<<<512, 256, 0, stream>>>(Q, Kb, Vtb, Opart, lpart, maskp);
    reduce_kernel<<<512, 256, 0, stream>>>(Opart, lpart, Pv, ctxb, maskp);
    proj_kernel<<<dim3(8, 64), 256, 0, stream>>>(ctxb, Wob, Wb, out);
}